// Round 2
// baseline (157.930 us; speedup 1.0000x reference)
//
#include <hip/hip_runtime.h>

#define NN 50000
#define NE 1600000
#define FIN 128
#define FOUT 64
#define SLOPE 0.2f

#define NPB  64              // nodes per bucket (power of 2: bucket = dst>>6)
#define NB   782             // ceil(50000/64) buckets
#define CAP  2560            // per-bucket edge cap (mean 2048, sd ~45 -> +11 sigma)
#define FBLK 65              // fill blocks: 24.6K edges each -> 31-edge (124 B) runs
#define CHC4 6154            // int4 edge-quads per fill block (65*6154 >= 400000)
#define GBLK 782             // gemm blocks, 64 nodes each
#define LW   136             // gemm LDS row stride in bf16 units (272 B)

typedef unsigned int u32;
typedef short short8 __attribute__((ext_vector_type(8)));
typedef float f32x4 __attribute__((ext_vector_type(4)));

__device__ __forceinline__ unsigned short f2bf(float f) {   // RTNE
    u32 u = __float_as_uint(f);
    u += 0x7FFFu + ((u >> 16) & 1u);
    return (unsigned short)(u >> 16);
}
__device__ __forceinline__ float bf2f(unsigned short s) {
    return __uint_as_float(((u32)s) << 16);
}

union FusedLds {
    unsigned short Wt[64 * LW];                     // 17.4 KB (gemm branch)
    struct { int cnt[NB]; int gb[NB]; int cur[NB]; } f;  // 9.4 KB (fill)
};

// blocks [0, FBLK): SINGLE-PASS binning straight to 64-node buckets.
//   bucket = dst>>6 (shift, no magic div). FBLK=65 so each block owns ~24.6K
//   edges -> ~31-edge (124 B) runs per bucket: near-full-line writes (R12
//   lesson: sub-line runs cause cross-XCD partial-line write amplification).
// blocks [FBLK, ..): h = x@W bf16 MFMA + a_src/a_dst (fp32 acc). Unchanged.
__global__ __launch_bounds__(256) void fused_k(
        const float* __restrict__ x, const float* __restrict__ W,
        const float* __restrict__ att_s, const float* __restrict__ att_d,
        const int* __restrict__ ei, int* __restrict__ ccur,
        u32* __restrict__ cstage, unsigned short* __restrict__ h,
        float* __restrict__ a_src, float* __restrict__ a_dst) {
    __shared__ FusedLds L;
    const int tid = threadIdx.x;

    if (blockIdx.x < FBLK) {
        for (int i = tid; i < NB; i += 256) L.f.cnt[i] = 0;
        __syncthreads();
        const int4* sd4 = (const int4*)(ei + NE);
        const int4* ss4 = (const int4*)ei;
        const int lo = blockIdx.x * CHC4, hi = min(NE / 4, lo + CHC4);
        for (int i = lo + tid; i < hi; i += 256) {
            int4 d = sd4[i];
            atomicAdd(&L.f.cnt[d.x >> 6], 1);
            atomicAdd(&L.f.cnt[d.y >> 6], 1);
            atomicAdd(&L.f.cnt[d.z >> 6], 1);
            atomicAdd(&L.f.cnt[d.w >> 6], 1);
        }
        __syncthreads();
        for (int b = tid; b < NB; b += 256) {
            int tot = L.f.cnt[b];
            L.f.gb[b] = tot ? atomicAdd(&ccur[b], tot) : 0;
            L.f.cur[b] = 0;
        }
        __syncthreads();
        for (int i = lo + tid; i < hi; i += 256) {
            int4 d = sd4[i];
            int4 s = ss4[i];
            int b, pos;
            b = d.x >> 6; pos = L.f.gb[b] + atomicAdd(&L.f.cur[b], 1);
            if (pos < CAP) cstage[(size_t)b * CAP + pos] = (u32)s.x | ((u32)(d.x & 63) << 16);
            b = d.y >> 6; pos = L.f.gb[b] + atomicAdd(&L.f.cur[b], 1);
            if (pos < CAP) cstage[(size_t)b * CAP + pos] = (u32)s.y | ((u32)(d.y & 63) << 16);
            b = d.z >> 6; pos = L.f.gb[b] + atomicAdd(&L.f.cur[b], 1);
            if (pos < CAP) cstage[(size_t)b * CAP + pos] = (u32)s.z | ((u32)(d.z & 63) << 16);
            b = d.w >> 6; pos = L.f.gb[b] + atomicAdd(&L.f.cur[b], 1);
            if (pos < CAP) cstage[(size_t)b * CAP + pos] = (u32)s.w | ((u32)(d.w & 63) << 16);
        }
    } else {
        unsigned short* Wt = L.Wt;
        const int node0 = (blockIdx.x - FBLK) * 64;
        for (int i = tid; i < 128 * 16; i += 256) {   // stage W^T as bf16
            int k = i >> 4, f = (i & 15) * 4;
            float4 w4 = ((const float4*)W)[i];        // W[k][f..f+3]
            Wt[(f + 0) * LW + k] = f2bf(w4.x);
            Wt[(f + 1) * LW + k] = f2bf(w4.y);
            Wt[(f + 2) * LW + k] = f2bf(w4.z);
            Wt[(f + 3) * LW + k] = f2bf(w4.w);
        }
        const int wv = tid >> 6, lane = tid & 63;
        const int q = lane >> 4, mr = lane & 15;
        const int row = node0 + wv * 16 + mr;
        const bool valid = row < NN;
        const float4* x4 = (const float4*)x;

        short8 afr[4];                                // A-frags direct from global
        #pragma unroll
        for (int ks = 0; ks < 4; ++ks) {
            float4 f0 = make_float4(0.f, 0.f, 0.f, 0.f), f1 = f0;
            if (valid) {
                f0 = x4[(size_t)row * 32 + ks * 8 + q * 2];
                f1 = x4[(size_t)row * 32 + ks * 8 + q * 2 + 1];
            }
            short8 a;
            a[0] = (short)f2bf(f0.x); a[1] = (short)f2bf(f0.y);
            a[2] = (short)f2bf(f0.z); a[3] = (short)f2bf(f0.w);
            a[4] = (short)f2bf(f1.x); a[5] = (short)f2bf(f1.y);
            a[6] = (short)f2bf(f1.z); a[7] = (short)f2bf(f1.w);
            afr[ks] = a;
        }
        __syncthreads();

        f32x4 acc[4] = {{0,0,0,0},{0,0,0,0},{0,0,0,0},{0,0,0,0}};
        #pragma unroll
        for (int ks = 0; ks < 4; ++ks) {
            #pragma unroll
            for (int nt = 0; nt < 4; ++nt) {
                short8 b = *(const short8*)(Wt + (nt * 16 + mr) * LW + ks * 32 + q * 8);
                acc[nt] = __builtin_amdgcn_mfma_f32_16x16x32_bf16(afr[ks], b, acc[nt], 0, 0, 0);
            }
        }
        float atts[4], attd[4];
        #pragma unroll
        for (int nt = 0; nt < 4; ++nt) {
            atts[nt] = att_s[nt * 16 + mr];
            attd[nt] = att_d[nt * 16 + mr];
        }
        #pragma unroll
        for (int r = 0; r < 4; ++r) {
            int node = node0 + wv * 16 + q * 4 + r;   // C-layout row
            float ps = 0.f, pd = 0.f;
            #pragma unroll
            for (int nt = 0; nt < 4; ++nt) {
                float v = acc[nt][r];
                if (node < NN) h[(size_t)node * 64 + nt * 16 + mr] = f2bf(v);
                ps += v * atts[nt];
                pd += v * attd[nt];
            }
            #pragma unroll
            for (int off = 8; off > 0; off >>= 1) {
                ps += __shfl_xor(ps, off);
                pd += __shfl_xor(pd, off);
            }
            if (mr == 0 && node < NN) { a_src[node] = ps; a_dst[node] = pd; }
        }
    }
}

// one 1024-thread block per 64-node bucket: node-local CSR in LDS, then one
// 16-lane quad per node (64 quads = 64 nodes), lane = 4 features, ushort4 h
// loads, float4 out store. 1024 threads -> 2 blocks/CU resident = 32 waves/CU
// (R1 lesson: 256-thread x 782 blocks left only ~12 waves/CU for the
// latency-bound gather). LDS 15.9 KB.
__global__ __launch_bounds__(1024) void agg_k(
        const u32* __restrict__ staging, const int* __restrict__ bcur,
        const float* __restrict__ a_src, const float* __restrict__ a_dst,
        const ushort4* __restrict__ h4, const float* __restrict__ bias,
        float* __restrict__ out) {
    const int bkt = blockIdx.x;
    const int node0 = bkt << 6;
    const int nNodes = min(NPB, NN - node0);          // 64, or 16 in last bucket
    const int bsize = min(bcur[bkt], CAP);
    const u32* stg = staging + (size_t)bkt * CAP;
    const int tid = threadIdx.x, wv = tid >> 6, lane = tid & 63;

    __shared__ u32 pk[CAP];                           // 10 KB; aliased as evals
    __shared__ unsigned short ssrc[CAP];              // 5 KB
    __shared__ int lcnt[NPB];
    __shared__ int lbase[NPB + 1];
    __shared__ int lcur[NPB];
    float* evals = (float*)pk;

    for (int j = tid; j < bsize; j += 1024) pk[j] = stg[j];
    if (tid < NPB) lcnt[tid] = 0;
    __syncthreads();
    for (int j = tid; j < bsize; j += 1024)
        atomicAdd(&lcnt[pk[j] >> 16], 1);
    __syncthreads();
    if (tid < 64) {                                   // wave-0 scan (NPB=64)
        int v = lcnt[tid];
        #pragma unroll
        for (int off = 1; off < 64; off <<= 1) {
            int u = __shfl_up(v, off);
            if (tid >= off) v += u;
        }
        lbase[tid + 1] = v;
        if (tid == 0) lbase[0] = 0;
    }
    if (tid >= 64 && tid < 64 + NPB) lcur[tid - 64] = 0;
    __syncthreads();
    for (int j = tid; j < bsize; j += 1024) {
        u32 w = pk[j];
        int ld = w >> 16;
        int pos = lbase[ld] + atomicAdd(&lcur[ld], 1);
        ssrc[pos] = (unsigned short)(w & 0xFFFFu);
    }
    __syncthreads();                                  // pk dead; evals alias live

    const int q = lane >> 4, ql = lane & 15;
    const float4 b4 = ((const float4*)bias)[ql];
    const int ln = wv * 4 + q;                        // quad-uniform node [0,64)
    if (ln >= nNodes) return;
    const int n = node0 + ln;
    const int st = lbase[ln], deg = lbase[ln + 1] - st;
    const float ad = a_dst[n];
    float es = a_src[n] + ad; es = es > 0.f ? es : SLOPE * es;
    const float ps = __expf(es);                      // self-loop term
    float sum = 0.f;
    for (int j = ql; j < deg; j += 16) {
        int s = ssrc[st + j];
        float e = a_src[s] + ad; e = e > 0.f ? e : SLOPE * e;
        float pe = __expf(e);
        evals[st + j] = pe;
        sum += pe;
    }
    sum += __shfl_xor(sum, 8); sum += __shfl_xor(sum, 4);
    sum += __shfl_xor(sum, 2); sum += __shfl_xor(sum, 1);
    const float inv = 1.f / (sum + ps);

    ushort4 hs = h4[(size_t)n * 16 + ql];
    float a0 = ps * bf2f(hs.x), a1 = ps * bf2f(hs.y);
    float a2 = ps * bf2f(hs.z), a3 = ps * bf2f(hs.w);
    int j = 0;
    for (; j + 4 <= deg; j += 4) {                    // 4 gathers in flight
        int s0 = ssrc[st + j], s1 = ssrc[st + j + 1];
        int s2 = ssrc[st + j + 2], s3 = ssrc[st + j + 3];
        float e0 = evals[st + j], e1 = evals[st + j + 1];
        float e2 = evals[st + j + 2], e3 = evals[st + j + 3];
        ushort4 v0 = h4[(size_t)s0 * 16 + ql];
        ushort4 v1 = h4[(size_t)s1 * 16 + ql];
        ushort4 v2 = h4[(size_t)s2 * 16 + ql];
        ushort4 v3 = h4[(size_t)s3 * 16 + ql];
        a0 += e0 * bf2f(v0.x); a1 += e0 * bf2f(v0.y);
        a2 += e0 * bf2f(v0.z); a3 += e0 * bf2f(v0.w);
        a0 += e1 * bf2f(v1.x); a1 += e1 * bf2f(v1.y);
        a2 += e1 * bf2f(v1.z); a3 += e1 * bf2f(v1.w);
        a0 += e2 * bf2f(v2.x); a1 += e2 * bf2f(v2.y);
        a2 += e2 * bf2f(v2.z); a3 += e2 * bf2f(v2.w);
        a0 += e3 * bf2f(v3.x); a1 += e3 * bf2f(v3.y);
        a2 += e3 * bf2f(v3.z); a3 += e3 * bf2f(v3.w);
    }
    for (; j < deg; ++j) {
        int s = ssrc[st + j];
        float ev = evals[st + j];
        ushort4 hv = h4[(size_t)s * 16 + ql];
        a0 += ev * bf2f(hv.x); a1 += ev * bf2f(hv.y);
        a2 += ev * bf2f(hv.z); a3 += ev * bf2f(hv.w);
    }
    float4 o;
    o.x = a0 * inv + b4.x; o.x = o.x > 0.f ? o.x : 0.f;
    o.y = a1 * inv + b4.y; o.y = o.y > 0.f ? o.y : 0.f;
    o.z = a2 * inv + b4.z; o.z = o.z > 0.f ? o.z : 0.f;
    o.w = a3 * inv + b4.w; o.w = o.w > 0.f ? o.w : 0.f;
    ((float4*)out)[(size_t)n * 16 + ql] = o;
}

extern "C" void kernel_launch(void* const* d_in, const int* in_sizes, int n_in,
                              void* d_out, int out_size, void* d_ws, size_t ws_size,
                              hipStream_t stream) {
    const float* x     = (const float*)d_in[0];
    const int*   ei    = (const int*)d_in[1];     // int32 (harness converts)
    const float* W     = (const float*)d_in[2];
    const float* att_s = (const float*)d_in[3];
    const float* att_d = (const float*)d_in[4];
    const float* bias  = (const float*)d_in[5];
    float* out = (float*)d_out;

    // ws: h[NN*64] bf16 (6.4MB) | a_src | a_dst (0.4MB) | ccur[1024]
    //     | cstage[782*2560] u32 (8.0MB)
    unsigned short* h = (unsigned short*)d_ws;
    float* a_src  = (float*)(h + (size_t)NN * 64);
    float* a_dst  = a_src + NN;
    int*   ccur   = (int*)(a_dst + NN);
    u32*   cstage = (u32*)(ccur + 1024);

    hipMemsetAsync(ccur, 0, NB * sizeof(int), stream);

    fused_k<<<FBLK + GBLK, 256, 0, stream>>>(x, W, att_s, att_d, ei, ccur,
                                             cstage, h, a_src, a_dst);
    agg_k<<<NB, 1024, 0, stream>>>(cstage, ccur, a_src, a_dst,
                                   (const ushort4*)h, bias, out);
}

// Round 3
// 148.733 us; speedup vs baseline: 1.0618x; 1.0618x over previous
//
#include <hip/hip_runtime.h>

#define NN 50000
#define NE 1600000
#define FIN 128
#define FOUT 64
#define SLOPE 0.2f

#define NPB  64              // nodes per bucket (power of 2: bucket = dst>>6)
#define NB   782             // ceil(50000/64) buckets
#define CAP  2560            // per-bucket edge cap (mean 2048, sd ~45 -> +11 sigma)
#define FBLK 261             // fill blocks (R2 lesson: 65 -> 40us serialization tail)
#define CHC4 1536            // int4 edge-quads per fill block (6144 edges)
#define GBLK 782             // gemm blocks, 64 nodes each
#define LW   136             // gemm LDS row stride in bf16 units (272 B)

typedef unsigned int u32;
typedef short short8 __attribute__((ext_vector_type(8)));
typedef float f32x4 __attribute__((ext_vector_type(4)));

__device__ __forceinline__ unsigned short f2bf(float f) {   // RTNE
    u32 u = __float_as_uint(f);
    u += 0x7FFFu + ((u >> 16) & 1u);
    return (unsigned short)(u >> 16);
}
__device__ __forceinline__ float bf2f(unsigned short s) {
    return __uint_as_float(((u32)s) << 16);
}

union FusedLds {
    unsigned short Wt[64 * LW];                     // 17.4 KB (gemm branch)
    struct { int cnt[NB]; int gb[NB]; int cur[NB]; } f;  // 9.4 KB (fill)
};

// blocks [0, FBLK): SINGLE-PASS binning straight to 64-node buckets.
//   bucket = dst>>6 (shift, no magic div). FBLK=261: fill blocks spread ~1/CU
//   and overlap the gemm blocks; R2's FBLK=65 concentrated the scatter on 65
//   CUs -> 40us tail at 3% occupancy. HBM counters (R2) show L2 absorbs the
//   sub-line scatter runs (WRITE_SIZE == logical bytes), so short runs are fine.
// blocks [FBLK, ..): h = x@W bf16 MFMA + a_src/a_dst (fp32 acc). Unchanged.
__global__ __launch_bounds__(256) void fused_k(
        const float* __restrict__ x, const float* __restrict__ W,
        const float* __restrict__ att_s, const float* __restrict__ att_d,
        const int* __restrict__ ei, int* __restrict__ ccur,
        u32* __restrict__ cstage, unsigned short* __restrict__ h,
        float* __restrict__ a_src, float* __restrict__ a_dst) {
    __shared__ FusedLds L;
    const int tid = threadIdx.x;

    if (blockIdx.x < FBLK) {
        for (int i = tid; i < NB; i += 256) L.f.cnt[i] = 0;
        __syncthreads();
        const int4* sd4 = (const int4*)(ei + NE);
        const int4* ss4 = (const int4*)ei;
        const int lo = blockIdx.x * CHC4, hi = min(NE / 4, lo + CHC4);
        for (int i = lo + tid; i < hi; i += 256) {
            int4 d = sd4[i];
            atomicAdd(&L.f.cnt[d.x >> 6], 1);
            atomicAdd(&L.f.cnt[d.y >> 6], 1);
            atomicAdd(&L.f.cnt[d.z >> 6], 1);
            atomicAdd(&L.f.cnt[d.w >> 6], 1);
        }
        __syncthreads();
        for (int b = tid; b < NB; b += 256) {
            int tot = L.f.cnt[b];
            L.f.gb[b] = tot ? atomicAdd(&ccur[b], tot) : 0;
            L.f.cur[b] = 0;
        }
        __syncthreads();
        for (int i = lo + tid; i < hi; i += 256) {
            int4 d = sd4[i];
            int4 s = ss4[i];
            int b, pos;
            b = d.x >> 6; pos = L.f.gb[b] + atomicAdd(&L.f.cur[b], 1);
            if (pos < CAP) cstage[(size_t)b * CAP + pos] = (u32)s.x | ((u32)(d.x & 63) << 16);
            b = d.y >> 6; pos = L.f.gb[b] + atomicAdd(&L.f.cur[b], 1);
            if (pos < CAP) cstage[(size_t)b * CAP + pos] = (u32)s.y | ((u32)(d.y & 63) << 16);
            b = d.z >> 6; pos = L.f.gb[b] + atomicAdd(&L.f.cur[b], 1);
            if (pos < CAP) cstage[(size_t)b * CAP + pos] = (u32)s.z | ((u32)(d.z & 63) << 16);
            b = d.w >> 6; pos = L.f.gb[b] + atomicAdd(&L.f.cur[b], 1);
            if (pos < CAP) cstage[(size_t)b * CAP + pos] = (u32)s.w | ((u32)(d.w & 63) << 16);
        }
    } else {
        unsigned short* Wt = L.Wt;
        const int node0 = (blockIdx.x - FBLK) * 64;
        for (int i = tid; i < 128 * 16; i += 256) {   // stage W^T as bf16
            int k = i >> 4, f = (i & 15) * 4;
            float4 w4 = ((const float4*)W)[i];        // W[k][f..f+3]
            Wt[(f + 0) * LW + k] = f2bf(w4.x);
            Wt[(f + 1) * LW + k] = f2bf(w4.y);
            Wt[(f + 2) * LW + k] = f2bf(w4.z);
            Wt[(f + 3) * LW + k] = f2bf(w4.w);
        }
        const int wv = tid >> 6, lane = tid & 63;
        const int q = lane >> 4, mr = lane & 15;
        const int row = node0 + wv * 16 + mr;
        const bool valid = row < NN;
        const float4* x4 = (const float4*)x;

        short8 afr[4];                                // A-frags direct from global
        #pragma unroll
        for (int ks = 0; ks < 4; ++ks) {
            float4 f0 = make_float4(0.f, 0.f, 0.f, 0.f), f1 = f0;
            if (valid) {
                f0 = x4[(size_t)row * 32 + ks * 8 + q * 2];
                f1 = x4[(size_t)row * 32 + ks * 8 + q * 2 + 1];
            }
            short8 a;
            a[0] = (short)f2bf(f0.x); a[1] = (short)f2bf(f0.y);
            a[2] = (short)f2bf(f0.z); a[3] = (short)f2bf(f0.w);
            a[4] = (short)f2bf(f1.x); a[5] = (short)f2bf(f1.y);
            a[6] = (short)f2bf(f1.z); a[7] = (short)f2bf(f1.w);
            afr[ks] = a;
        }
        __syncthreads();

        f32x4 acc[4] = {{0,0,0,0},{0,0,0,0},{0,0,0,0},{0,0,0,0}};
        #pragma unroll
        for (int ks = 0; ks < 4; ++ks) {
            #pragma unroll
            for (int nt = 0; nt < 4; ++nt) {
                short8 b = *(const short8*)(Wt + (nt * 16 + mr) * LW + ks * 32 + q * 8);
                acc[nt] = __builtin_amdgcn_mfma_f32_16x16x32_bf16(afr[ks], b, acc[nt], 0, 0, 0);
            }
        }
        float atts[4], attd[4];
        #pragma unroll
        for (int nt = 0; nt < 4; ++nt) {
            atts[nt] = att_s[nt * 16 + mr];
            attd[nt] = att_d[nt * 16 + mr];
        }
        #pragma unroll
        for (int r = 0; r < 4; ++r) {
            int node = node0 + wv * 16 + q * 4 + r;   // C-layout row
            float ps = 0.f, pd = 0.f;
            #pragma unroll
            for (int nt = 0; nt < 4; ++nt) {
                float v = acc[nt][r];
                if (node < NN) h[(size_t)node * 64 + nt * 16 + mr] = f2bf(v);
                ps += v * atts[nt];
                pd += v * attd[nt];
            }
            #pragma unroll
            for (int off = 8; off > 0; off >>= 1) {
                ps += __shfl_xor(ps, off);
                pd += __shfl_xor(pd, off);
            }
            if (mr == 0 && node < NN) { a_src[node] = ps; a_dst[node] = pd; }
        }
    }
}

// one 512-thread block per 64-node bucket: node-local CSR in LDS, then one
// 16-lane quad per 2 consecutive nodes (32 quads), lane = 4 features, ushort4
// h loads, float4 out store. 512t x 782 blocks = 400K threads < 524K chip
// capacity: ALL blocks resident (no scheduling rounds; R2's 1024t had a
// 1.53-round tail), 24.4 waves/CU hiding gather latency. LDS 15.9 KB -> 4
// blocks/CU thread-limited.
__global__ __launch_bounds__(512) void agg_k(
        const u32* __restrict__ staging, const int* __restrict__ bcur,
        const float* __restrict__ a_src, const float* __restrict__ a_dst,
        const ushort4* __restrict__ h4, const float* __restrict__ bias,
        float* __restrict__ out) {
    const int bkt = blockIdx.x;
    const int node0 = bkt << 6;
    const int nNodes = min(NPB, NN - node0);          // 64, or 16 in last bucket
    const int bsize = min(bcur[bkt], CAP);
    const u32* stg = staging + (size_t)bkt * CAP;
    const int tid = threadIdx.x, wv = tid >> 6, lane = tid & 63;

    __shared__ u32 pk[CAP];                           // 10 KB; aliased as evals
    __shared__ unsigned short ssrc[CAP];              // 5 KB
    __shared__ int lcnt[NPB];
    __shared__ int lbase[NPB + 1];
    __shared__ int lcur[NPB];
    float* evals = (float*)pk;

    for (int j = tid; j < bsize; j += 512) pk[j] = stg[j];
    if (tid < NPB) lcnt[tid] = 0;
    __syncthreads();
    for (int j = tid; j < bsize; j += 512)
        atomicAdd(&lcnt[pk[j] >> 16], 1);
    __syncthreads();
    if (tid < 64) {                                   // wave-0 scan (NPB=64)
        int v = lcnt[tid];
        #pragma unroll
        for (int off = 1; off < 64; off <<= 1) {
            int u = __shfl_up(v, off);
            if (tid >= off) v += u;
        }
        lbase[tid + 1] = v;
        if (tid == 0) lbase[0] = 0;
    }
    if (tid >= 64 && tid < 64 + NPB) lcur[tid - 64] = 0;
    __syncthreads();
    for (int j = tid; j < bsize; j += 512) {
        u32 w = pk[j];
        int ld = w >> 16;
        int pos = lbase[ld] + atomicAdd(&lcur[ld], 1);
        ssrc[pos] = (unsigned short)(w & 0xFFFFu);
    }
    __syncthreads();                                  // pk dead; evals alias live

    const int q = lane >> 4, ql = lane & 15;
    const float4 b4 = ((const float4*)bias)[ql];
    const int quad = wv * 4 + q;                      // [0,32)
    #pragma unroll
    for (int t = 0; t < 2; ++t) {
        const int ln = quad * 2 + t;                  // 2 consecutive nodes/quad
        if (ln >= nNodes) continue;
        const int n = node0 + ln;
        const int st = lbase[ln], deg = lbase[ln + 1] - st;
        const float ad = a_dst[n];
        float es = a_src[n] + ad; es = es > 0.f ? es : SLOPE * es;
        const float ps = __expf(es);                  // self-loop term
        float sum = 0.f;
        for (int j = ql; j < deg; j += 16) {
            int s = ssrc[st + j];
            float e = a_src[s] + ad; e = e > 0.f ? e : SLOPE * e;
            float pe = __expf(e);
            evals[st + j] = pe;
            sum += pe;
        }
        sum += __shfl_xor(sum, 8); sum += __shfl_xor(sum, 4);
        sum += __shfl_xor(sum, 2); sum += __shfl_xor(sum, 1);
        const float inv = 1.f / (sum + ps);

        ushort4 hs = h4[(size_t)n * 16 + ql];
        float a0 = ps * bf2f(hs.x), a1 = ps * bf2f(hs.y);
        float a2 = ps * bf2f(hs.z), a3 = ps * bf2f(hs.w);
        int j = 0;
        for (; j + 4 <= deg; j += 4) {                // 4 gathers in flight
            int s0 = ssrc[st + j], s1 = ssrc[st + j + 1];
            int s2 = ssrc[st + j + 2], s3 = ssrc[st + j + 3];
            float e0 = evals[st + j], e1 = evals[st + j + 1];
            float e2 = evals[st + j + 2], e3 = evals[st + j + 3];
            ushort4 v0 = h4[(size_t)s0 * 16 + ql];
            ushort4 v1 = h4[(size_t)s1 * 16 + ql];
            ushort4 v2 = h4[(size_t)s2 * 16 + ql];
            ushort4 v3 = h4[(size_t)s3 * 16 + ql];
            a0 += e0 * bf2f(v0.x); a1 += e0 * bf2f(v0.y);
            a2 += e0 * bf2f(v0.z); a3 += e0 * bf2f(v0.w);
            a0 += e1 * bf2f(v1.x); a1 += e1 * bf2f(v1.y);
            a2 += e1 * bf2f(v1.z); a3 += e1 * bf2f(v1.w);
            a0 += e2 * bf2f(v2.x); a1 += e2 * bf2f(v2.y);
            a2 += e2 * bf2f(v2.z); a3 += e2 * bf2f(v2.w);
            a0 += e3 * bf2f(v3.x); a1 += e3 * bf2f(v3.y);
            a2 += e3 * bf2f(v3.z); a3 += e3 * bf2f(v3.w);
        }
        for (; j < deg; ++j) {
            int s = ssrc[st + j];
            float ev = evals[st + j];
            ushort4 hv = h4[(size_t)s * 16 + ql];
            a0 += ev * bf2f(hv.x); a1 += ev * bf2f(hv.y);
            a2 += ev * bf2f(hv.z); a3 += ev * bf2f(hv.w);
        }
        float4 o;
        o.x = a0 * inv + b4.x; o.x = o.x > 0.f ? o.x : 0.f;
        o.y = a1 * inv + b4.y; o.y = o.y > 0.f ? o.y : 0.f;
        o.z = a2 * inv + b4.z; o.z = o.z > 0.f ? o.z : 0.f;
        o.w = a3 * inv + b4.w; o.w = o.w > 0.f ? o.w : 0.f;
        ((float4*)out)[(size_t)n * 16 + ql] = o;
    }
}

extern "C" void kernel_launch(void* const* d_in, const int* in_sizes, int n_in,
                              void* d_out, int out_size, void* d_ws, size_t ws_size,
                              hipStream_t stream) {
    const float* x     = (const float*)d_in[0];
    const int*   ei    = (const int*)d_in[1];     // int32 (harness converts)
    const float* W     = (const float*)d_in[2];
    const float* att_s = (const float*)d_in[3];
    const float* att_d = (const float*)d_in[4];
    const float* bias  = (const float*)d_in[5];
    float* out = (float*)d_out;

    // ws: h[NN*64] bf16 (6.4MB) | a_src | a_dst (0.4MB) | ccur[1024]
    //     | cstage[782*2560] u32 (8.0MB)
    unsigned short* h = (unsigned short*)d_ws;
    float* a_src  = (float*)(h + (size_t)NN * 64);
    float* a_dst  = a_src + NN;
    int*   ccur   = (int*)(a_dst + NN);
    u32*   cstage = (u32*)(ccur + 1024);

    hipMemsetAsync(ccur, 0, NB * sizeof(int), stream);

    fused_k<<<FBLK + GBLK, 256, 0, stream>>>(x, W, att_s, att_d, ei, ccur,
                                             cstage, h, a_src, a_dst);
    agg_k<<<NB, 512, 0, stream>>>(cstage, ccur, a_src, a_dst,
                                  (const ushort4*)h, bias, out);
}

// Round 4
// 146.643 us; speedup vs baseline: 1.0770x; 1.0142x over previous
//
#include <hip/hip_runtime.h>

#define NN 50000
#define NE 1600000
#define FIN 128
#define FOUT 64
#define SLOPE 0.2f

#define NPB  16              // nodes per fine bucket (bucket = dst>>4)
#define NBF  3125            // 50000/16 exactly
#define CAPB 768             // fine cap (mean 512, sd ~23 -> +11 sigma)
#define FBLK 261             // fill blocks (R2 lesson: fewer -> serialization tail)
#define CHC4 1536            // int4 edge-quads per fill block (6144 edges)
#define GBLK 782             // gemm blocks, 64 nodes each
#define LW   136             // gemm LDS row stride in bf16 units (272 B)

typedef unsigned int u32;
typedef short short8 __attribute__((ext_vector_type(8)));
typedef float f32x4 __attribute__((ext_vector_type(4)));

__device__ __forceinline__ unsigned short f2bf(float f) {   // RTNE
    u32 u = __float_as_uint(f);
    u += 0x7FFFu + ((u >> 16) & 1u);
    return (unsigned short)(u >> 16);
}
__device__ __forceinline__ float bf2f(unsigned short s) {
    return __uint_as_float(((u32)s) << 16);
}

union FusedLds {
    unsigned short Wt[64 * LW];                     // 17.4 KB (gemm branch)
    struct { int cnt[NBF]; int gb[NBF]; } f;        // 25.0 KB (fill; cnt reused as cursor)
};

// blocks [0, FBLK): DIRECT binning into the 3125 fine 16-node buckets.
//   R2 counter evidence: L2 absorbs sub-line scatter runs (WRITE_SIZE ==
//   logical bytes), so the former coarse->fine two-level scheme (which existed
//   to lengthen runs) is unnecessary — fine_k deleted, one edge pass saved.
//   LDS histogram over 3125 bins (atomic contention negligible), one global
//   fcur atomic per nonzero bin (~2.7K/block, ~710K total over LLC banks).
// blocks [FBLK, ..): h = x@W bf16 MFMA + a_src/a_dst (fp32 acc). Unchanged.
__global__ __launch_bounds__(256) void fused_k(
        const float* __restrict__ x, const float* __restrict__ W,
        const float* __restrict__ att_s, const float* __restrict__ att_d,
        const int* __restrict__ ei, int* __restrict__ fcur,
        u32* __restrict__ fstage, unsigned short* __restrict__ h,
        float* __restrict__ a_src, float* __restrict__ a_dst) {
    __shared__ FusedLds L;
    const int tid = threadIdx.x;

    if (blockIdx.x < FBLK) {
        for (int i = tid; i < NBF; i += 256) L.f.cnt[i] = 0;
        __syncthreads();
        const int4* sd4 = (const int4*)(ei + NE);
        const int4* ss4 = (const int4*)ei;
        const int lo = blockIdx.x * CHC4, hi = min(NE / 4, lo + CHC4);
        for (int i = lo + tid; i < hi; i += 256) {
            int4 d = sd4[i];
            atomicAdd(&L.f.cnt[d.x >> 4], 1);
            atomicAdd(&L.f.cnt[d.y >> 4], 1);
            atomicAdd(&L.f.cnt[d.z >> 4], 1);
            atomicAdd(&L.f.cnt[d.w >> 4], 1);
        }
        __syncthreads();
        for (int b = tid; b < NBF; b += 256) {
            int tot = L.f.cnt[b];
            L.f.gb[b] = tot ? atomicAdd(&fcur[b], tot) : 0;
            L.f.cnt[b] = 0;                           // reuse as scatter cursor
        }
        __syncthreads();
        for (int i = lo + tid; i < hi; i += 256) {
            int4 d = sd4[i];
            int4 s = ss4[i];
            int b, pos;
            b = d.x >> 4; pos = L.f.gb[b] + atomicAdd(&L.f.cnt[b], 1);
            if (pos < CAPB) fstage[(size_t)b * CAPB + pos] = (u32)s.x | ((u32)(d.x & 15) << 16);
            b = d.y >> 4; pos = L.f.gb[b] + atomicAdd(&L.f.cnt[b], 1);
            if (pos < CAPB) fstage[(size_t)b * CAPB + pos] = (u32)s.y | ((u32)(d.y & 15) << 16);
            b = d.z >> 4; pos = L.f.gb[b] + atomicAdd(&L.f.cnt[b], 1);
            if (pos < CAPB) fstage[(size_t)b * CAPB + pos] = (u32)s.z | ((u32)(d.z & 15) << 16);
            b = d.w >> 4; pos = L.f.gb[b] + atomicAdd(&L.f.cnt[b], 1);
            if (pos < CAPB) fstage[(size_t)b * CAPB + pos] = (u32)s.w | ((u32)(d.w & 15) << 16);
        }
    } else {
        unsigned short* Wt = L.Wt;
        const int node0 = (blockIdx.x - FBLK) * 64;
        for (int i = tid; i < 128 * 16; i += 256) {   // stage W^T as bf16
            int k = i >> 4, f = (i & 15) * 4;
            float4 w4 = ((const float4*)W)[i];        // W[k][f..f+3]
            Wt[(f + 0) * LW + k] = f2bf(w4.x);
            Wt[(f + 1) * LW + k] = f2bf(w4.y);
            Wt[(f + 2) * LW + k] = f2bf(w4.z);
            Wt[(f + 3) * LW + k] = f2bf(w4.w);
        }
        const int wv = tid >> 6, lane = tid & 63;
        const int q = lane >> 4, mr = lane & 15;
        const int row = node0 + wv * 16 + mr;
        const bool valid = row < NN;
        const float4* x4 = (const float4*)x;

        short8 afr[4];                                // A-frags direct from global
        #pragma unroll
        for (int ks = 0; ks < 4; ++ks) {
            float4 f0 = make_float4(0.f, 0.f, 0.f, 0.f), f1 = f0;
            if (valid) {
                f0 = x4[(size_t)row * 32 + ks * 8 + q * 2];
                f1 = x4[(size_t)row * 32 + ks * 8 + q * 2 + 1];
            }
            short8 a;
            a[0] = (short)f2bf(f0.x); a[1] = (short)f2bf(f0.y);
            a[2] = (short)f2bf(f0.z); a[3] = (short)f2bf(f0.w);
            a[4] = (short)f2bf(f1.x); a[5] = (short)f2bf(f1.y);
            a[6] = (short)f2bf(f1.z); a[7] = (short)f2bf(f1.w);
            afr[ks] = a;
        }
        __syncthreads();

        f32x4 acc[4] = {{0,0,0,0},{0,0,0,0},{0,0,0,0},{0,0,0,0}};
        #pragma unroll
        for (int ks = 0; ks < 4; ++ks) {
            #pragma unroll
            for (int nt = 0; nt < 4; ++nt) {
                short8 b = *(const short8*)(Wt + (nt * 16 + mr) * LW + ks * 32 + q * 8);
                acc[nt] = __builtin_amdgcn_mfma_f32_16x16x32_bf16(afr[ks], b, acc[nt], 0, 0, 0);
            }
        }
        float atts[4], attd[4];
        #pragma unroll
        for (int nt = 0; nt < 4; ++nt) {
            atts[nt] = att_s[nt * 16 + mr];
            attd[nt] = att_d[nt * 16 + mr];
        }
        #pragma unroll
        for (int r = 0; r < 4; ++r) {
            int node = node0 + wv * 16 + q * 4 + r;   // C-layout row
            float ps = 0.f, pd = 0.f;
            #pragma unroll
            for (int nt = 0; nt < 4; ++nt) {
                float v = acc[nt][r];
                if (node < NN) h[(size_t)node * 64 + nt * 16 + mr] = f2bf(v);
                ps += v * atts[nt];
                pd += v * attd[nt];
            }
            #pragma unroll
            for (int off = 8; off > 0; off >>= 1) {
                ps += __shfl_xor(ps, off);
                pd += __shfl_xor(pd, off);
            }
            if (mr == 0 && node < NN) { a_src[node] = ps; a_dst[node] = pd; }
        }
    }
}

// one block per 16-node fine bucket (R0's proven geometry): node-local CSR in
// LDS, then one 16-lane quad per node (lane = 4 features, ushort4 h loads,
// float4 out store). 4.8 KB LDS, 3125 blocks, 8 blocks/CU = 32 waves/CU to
// hide gather latency.
__global__ __launch_bounds__(256) void agg_k(
        const u32* __restrict__ staging, const int* __restrict__ bcur,
        const float* __restrict__ a_src, const float* __restrict__ a_dst,
        const ushort4* __restrict__ h4, const float* __restrict__ bias,
        float* __restrict__ out) {
    const int bkt = blockIdx.x;
    const int node0 = bkt << 4;
    const int nNodes = min(NPB, NN - node0);
    const int bsize = min(bcur[bkt], CAPB);
    const u32* stg = staging + (size_t)bkt * CAPB;
    const int tid = threadIdx.x, wv = tid >> 6, lane = tid & 63;

    __shared__ u32 pk[CAPB];                          // packed; aliased as evals
    __shared__ unsigned short ssrc[CAPB];
    __shared__ int lcnt[NPB];
    __shared__ int lbase[NPB + 1];
    __shared__ int lcur[NPB];
    float* evals = (float*)pk;

    for (int j = tid; j < bsize; j += 256) pk[j] = stg[j];
    if (tid < NPB) lcnt[tid] = 0;
    __syncthreads();
    for (int j = tid; j < bsize; j += 256)
        atomicAdd(&lcnt[pk[j] >> 16], 1);
    __syncthreads();
    if (tid < 64) {                                   // wave-0 scan (NPB=16)
        int v = (tid < NPB) ? lcnt[tid] : 0;
        #pragma unroll
        for (int off = 1; off < NPB; off <<= 1) {
            int u = __shfl_up(v, off);
            if (tid >= off) v += u;
        }
        if (tid < NPB) lbase[tid + 1] = v;
        if (tid == 0) lbase[0] = 0;
    }
    if (tid >= 64 && tid < 64 + NPB) lcur[tid - 64] = 0;
    __syncthreads();
    for (int j = tid; j < bsize; j += 256) {
        u32 w = pk[j];
        int ld = w >> 16;
        int pos = lbase[ld] + atomicAdd(&lcur[ld], 1);
        ssrc[pos] = (unsigned short)(w & 0xFFFFu);
    }
    __syncthreads();                                  // pk dead; evals alias live

    const int q = lane >> 4, ql = lane & 15;
    const float4 b4 = ((const float4*)bias)[ql];
    const int ln = wv * 4 + q;                        // quad-uniform node [0,16)
    if (ln >= nNodes) return;
    const int n = node0 + ln;
    const int st = lbase[ln], deg = lbase[ln + 1] - st;
    const float ad = a_dst[n];
    float es = a_src[n] + ad; es = es > 0.f ? es : SLOPE * es;
    const float ps = __expf(es);                      // self-loop term
    float sum = 0.f;
    for (int j = ql; j < deg; j += 16) {
        int s = ssrc[st + j];
        float e = a_src[s] + ad; e = e > 0.f ? e : SLOPE * e;
        float pe = __expf(e);
        evals[st + j] = pe;
        sum += pe;
    }
    sum += __shfl_xor(sum, 8); sum += __shfl_xor(sum, 4);
    sum += __shfl_xor(sum, 2); sum += __shfl_xor(sum, 1);
    const float inv = 1.f / (sum + ps);

    ushort4 hs = h4[(size_t)n * 16 + ql];
    float a0 = ps * bf2f(hs.x), a1 = ps * bf2f(hs.y);
    float a2 = ps * bf2f(hs.z), a3 = ps * bf2f(hs.w);
    int j = 0;
    for (; j + 4 <= deg; j += 4) {                    // 4 gathers in flight
        int s0 = ssrc[st + j], s1 = ssrc[st + j + 1];
        int s2 = ssrc[st + j + 2], s3 = ssrc[st + j + 3];
        float e0 = evals[st + j], e1 = evals[st + j + 1];
        float e2 = evals[st + j + 2], e3 = evals[st + j + 3];
        ushort4 v0 = h4[(size_t)s0 * 16 + ql];
        ushort4 v1 = h4[(size_t)s1 * 16 + ql];
        ushort4 v2 = h4[(size_t)s2 * 16 + ql];
        ushort4 v3 = h4[(size_t)s3 * 16 + ql];
        a0 += e0 * bf2f(v0.x); a1 += e0 * bf2f(v0.y);
        a2 += e0 * bf2f(v0.z); a3 += e0 * bf2f(v0.w);
        a0 += e1 * bf2f(v1.x); a1 += e1 * bf2f(v1.y);
        a2 += e1 * bf2f(v1.z); a3 += e1 * bf2f(v1.w);
        a0 += e2 * bf2f(v2.x); a1 += e2 * bf2f(v2.y);
        a2 += e2 * bf2f(v2.z); a3 += e2 * bf2f(v2.w);
        a0 += e3 * bf2f(v3.x); a1 += e3 * bf2f(v3.y);
        a2 += e3 * bf2f(v3.z); a3 += e3 * bf2f(v3.w);
    }
    for (; j < deg; ++j) {
        int s = ssrc[st + j];
        float ev = evals[st + j];
        ushort4 hv = h4[(size_t)s * 16 + ql];
        a0 += ev * bf2f(hv.x); a1 += ev * bf2f(hv.y);
        a2 += ev * bf2f(hv.z); a3 += ev * bf2f(hv.w);
    }
    float4 o;
    o.x = a0 * inv + b4.x; o.x = o.x > 0.f ? o.x : 0.f;
    o.y = a1 * inv + b4.y; o.y = o.y > 0.f ? o.y : 0.f;
    o.z = a2 * inv + b4.z; o.z = o.z > 0.f ? o.z : 0.f;
    o.w = a3 * inv + b4.w; o.w = o.w > 0.f ? o.w : 0.f;
    ((float4*)out)[(size_t)n * 16 + ql] = o;
}

extern "C" void kernel_launch(void* const* d_in, const int* in_sizes, int n_in,
                              void* d_out, int out_size, void* d_ws, size_t ws_size,
                              hipStream_t stream) {
    const float* x     = (const float*)d_in[0];
    const int*   ei    = (const int*)d_in[1];     // int32 (harness converts)
    const float* W     = (const float*)d_in[2];
    const float* att_s = (const float*)d_in[3];
    const float* att_d = (const float*)d_in[4];
    const float* bias  = (const float*)d_in[5];
    float* out = (float*)d_out;

    // ws: h[NN*64] bf16 (6.4MB) | a_src | a_dst (0.4MB) | fcur[3200]
    //     | fstage[3125*768] u32 (9.6MB)
    unsigned short* h = (unsigned short*)d_ws;
    float* a_src  = (float*)(h + (size_t)NN * 64);
    float* a_dst  = a_src + NN;
    int*   fcur   = (int*)(a_dst + NN);
    u32*   fstage = (u32*)(fcur + 3200);

    hipMemsetAsync(fcur, 0, NBF * sizeof(int), stream);

    fused_k<<<FBLK + GBLK, 256, 0, stream>>>(x, W, att_s, att_d, ei, fcur,
                                             fstage, h, a_src, a_dst);
    agg_k<<<NBF, 256, 0, stream>>>(fstage, fcur, a_src, a_dst,
                                   (const ushort4*)h, bias, out);
}